// Round 13
// baseline (252.164 us; speedup 1.0000x reference)
//
#include <hip/hip_runtime.h>
#include <stdint.h>

#define BSZ 2
#define LSEQ 2048
#define DMOD 1024
#define NH 16
#define HDSZ 64
#define NT (LSEQ / 128)

typedef __attribute__((ext_vector_type(8))) short short8;
typedef __attribute__((ext_vector_type(4))) float f32x4;
typedef __attribute__((ext_vector_type(4))) unsigned short u16x4;
typedef __attribute__((ext_vector_type(4))) int i32x4;

#define MFMA16(a, b, c) __builtin_amdgcn_mfma_f32_16x16x32_bf16((a), (b), (c), 0, 0, 0)
#define EXP2F(x) __builtin_amdgcn_exp2f(x)

__device__ __forceinline__ unsigned short f2bf(float f) {
  union { float f; unsigned u; } x; x.f = f;
  unsigned u = x.u + 0x7fffu + ((x.u >> 16) & 1u);
  return (unsigned short)(u >> 16);
}

__device__ __forceinline__ unsigned cvt_pk_bf16(float lo, float hi) {
  unsigned r;
  asm("v_cvt_pk_bf16_f32 %0, %1, %2" : "=v"(r) : "v"(lo), "v"(hi));
  return r;
}

__device__ __forceinline__ short8 pack8_pk(f32x4 lo, f32x4 hi) {
  union { short8 s; unsigned u[4]; } r;
  r.u[0] = cvt_pk_bf16(lo[0], lo[1]);
  r.u[1] = cvt_pk_bf16(lo[2], lo[3]);
  r.u[2] = cvt_pk_bf16(hi[0], hi[1]);
  r.u[3] = cvt_pk_bf16(hi[2], hi[3]);
  return r.s;
}

__device__ __forceinline__ void gll16(const void* src, void* lds) {
  __builtin_amdgcn_global_load_lds((const __attribute__((address_space(1))) void*)src,
                                   (__attribute__((address_space(3))) void*)lds, 16, 0, 0);
}

// ---------------- GEMM: C = A * W^T + bias; z==3 = fused mask-check slice ----------
// v13: global_load_lds DMA staging (linear LDS dest, pre-swizzled global source).
// W (and A when AF32) staged as fp32, converted to bf16 at fragment-read time via
// v_cvt_pk_bf16_f32 (same RNE as before). A staged as bf16 when !AF32 (out-proj).
template <int AF32, int OUTF32>
__global__ __launch_bounds__(256) void gemm_bt(
    const void* __restrict__ A0, const void* __restrict__ A1, const void* __restrict__ A2,
    const float* __restrict__ W0, const float* __restrict__ W1, const float* __restrict__ W2,
    const float* __restrict__ b0, const float* __restrict__ b1, const float* __restrict__ b2,
    void* __restrict__ C0, void* __restrict__ C1, void* __restrict__ C2,
    float s0, float s1, float s2, int vtz, int M, int N, int K,
    const int* __restrict__ mask, int* __restrict__ flags) {
  const int z = blockIdx.z;
  const int tid = threadIdx.x;
  __shared__ int red[4];

  if (z == 3) {
    // mask-check slice: 256 blocks x 2 tiles of 128x128 (overlaps GEMM slices)
    const int t0 = (blockIdx.x + 32 * blockIdx.y) * 2;
#pragma unroll
    for (int t = t0; t < t0 + 2; ++t) {
      const int b_ = t >> 8, qt = (t >> 4) & 15, ktt = t & 15;
      const int r = tid >> 1, c = (tid & 1) * 64;
      const int* mr = mask + (size_t)b_ * LSEQ * LSEQ + (size_t)(qt * 128 + r) * LSEQ +
                      ktt * 128 + c;
      int ok = 1;
#pragma unroll
      for (int j = 0; j < 16; j++) {
        i32x4 v = __builtin_nontemporal_load((const i32x4*)(mr + j * 4));
        ok &= (v[0] != 0) & (v[1] != 0) & (v[2] != 0) & (v[3] != 0);
      }
      unsigned long long vote = __ballot(ok);
      if ((tid & 63) == 0) red[tid >> 6] = (vote == ~0ull) ? 1 : 0;
      __syncthreads();
      if (tid == 0) flags[(b_ * 16 + qt) * 16 + ktt] = red[0] & red[1] & red[2] & red[3];
      __syncthreads();
    }
    return;
  }

  const void* A = (z == 0) ? A0 : ((z == 1) ? A1 : A2);
  const float* W = (z == 0) ? W0 : ((z == 1) ? W1 : W2);
  const float* bias = (z == 0) ? b0 : ((z == 1) ? b1 : b2);
  void* Cout = (z == 0) ? C0 : ((z == 1) ? C1 : C2);
  const float scale = (z == 0) ? s0 : ((z == 1) ? s1 : s2);

  // LDS: Bs32 = 4096 floats (16 KB). AF32: As32 = 4096 floats; else As16 = 4096 ushorts.
  __shared__ __align__(16) float smem[AF32 ? 8192 : 6144];
  float* Bs32 = smem;
  float* As32 = smem + 4096;
  unsigned short* As16 = (unsigned short*)(smem + 4096);

  const int lane = tid & 63;
  const int wid = tid >> 6;
  const int bm = blockIdx.x, bn = blockIdx.y;
  const int wm = (wid >> 1) * 64, wn = (wid & 1) * 64;
  const int l15 = lane & 15, lg = lane >> 4;

  f32x4 acc[4][4];
#pragma unroll
  for (int i = 0; i < 4; i++)
#pragma unroll
    for (int j = 0; j < 4; j++) acc[i][j] = (f32x4){0.f, 0.f, 0.f, 0.f};

  // staging lane constants
  const int r8 = lane >> 3, c8 = lane & 7;  // fp32 staging: 8 rows / 1KB group
  const int r4 = lane >> 2, c4 = lane & 3;  // bf16 staging: 16 rows / 1KB group

  const float* Wg = W + (size_t)(bn * 128) * K;
  const float* Ag32 = (const float*)A + (size_t)(bm * 128) * K;
  const unsigned short* Ag16 = (const unsigned short*)A + (size_t)(bm * 128) * K;

  for (int k0 = 0; k0 < K; k0 += 32) {
    // ---- stage W (fp32 DMA, pre-swizzled source chunks) ----
#pragma unroll
    for (int gi = 0; gi < 4; gi++) {
      const int g = wid * 4 + gi;
      const int row = g * 8 + r8;
      const int ch = c8 ^ (row & 7);
      gll16(Wg + (size_t)row * K + k0 + ch * 4, Bs32 + g * 256);
    }
    // ---- stage A ----
    if constexpr (AF32) {
#pragma unroll
      for (int gi = 0; gi < 4; gi++) {
        const int g = wid * 4 + gi;
        const int row = g * 8 + r8;
        const int ch = c8 ^ (row & 7);
        gll16(Ag32 + (size_t)row * K + k0 + ch * 4, As32 + g * 256);
      }
    } else {
#pragma unroll
      for (int gi = 0; gi < 2; gi++) {
        const int g = wid * 2 + gi;
        const int row = g * 16 + r4;
        const int ch = c4 ^ (row & 3);
        gll16(Ag16 + (size_t)row * K + k0 + ch * 8, As16 + g * 512);
      }
    }
    __syncthreads();  // drains gll (vmcnt) + barrier

    short8 af[4], bf[4];
#pragma unroll
    for (int i = 0; i < 4; i++) {
      const int row = wm + i * 16 + l15;
      if constexpr (AF32) {
        f32x4 lo = *(const f32x4*)&As32[row * 32 + (((2 * lg) ^ (row & 7)) << 2)];
        f32x4 hi = *(const f32x4*)&As32[row * 32 + (((2 * lg + 1) ^ (row & 7)) << 2)];
        af[i] = pack8_pk(lo, hi);
      } else {
        af[i] = *(const short8*)&As16[row * 32 + ((lg ^ (row & 3)) << 3)];
      }
    }
#pragma unroll
    for (int j = 0; j < 4; j++) {
      const int row = wn + j * 16 + l15;
      f32x4 lo = *(const f32x4*)&Bs32[row * 32 + (((2 * lg) ^ (row & 7)) << 2)];
      f32x4 hi = *(const f32x4*)&Bs32[row * 32 + (((2 * lg + 1) ^ (row & 7)) << 2)];
      bf[j] = pack8_pk(lo, hi);
    }
#pragma unroll
    for (int i = 0; i < 4; i++)
#pragma unroll
      for (int j = 0; j < 4; j++) acc[i][j] = MFMA16(af[i], bf[j], acc[i][j]);
    __syncthreads();
  }

  const bool vtrans = (z == vtz);
  const int crow = bm * 128 + wm + ((lane >> 4) & 3) * 4;
#pragma unroll
  for (int j = 0; j < 4; j++) {
    const int col = bn * 128 + wn + j * 16 + (lane & 15);
    const float bv = bias[col];
#pragma unroll
    for (int i = 0; i < 4; i++) {
      if (OUTF32) {
#pragma unroll
        for (int r = 0; r < 4; r++) {
          float vvv = (acc[i][j][r] + bv) * scale;
          ((float*)Cout)[(size_t)(crow + i * 16 + r) * N + col] = vvv;
        }
      } else if (vtrans) {
        u16x4 pk;
#pragma unroll
        for (int r = 0; r < 4; r++) pk[r] = f2bf((acc[i][j][r] + bv) * scale);
        const int row = crow + i * 16;
        unsigned short* dst = (unsigned short*)Cout +
                              (size_t)(row >> 11) * DMOD * LSEQ + (size_t)col * LSEQ +
                              (row & (LSEQ - 1));
        *(u16x4*)dst = pk;
      } else {
#pragma unroll
        for (int r = 0; r < 4; r++) {
          float vvv = (acc[i][j][r] + bv) * scale;
          ((unsigned short*)Cout)[(size_t)(crow + i * 16 + r) * N + col] = f2bf(vvv);
        }
      }
    }
  }
}

// ---------------- fused attention (v12: coalesced attn stores via Ps readback) ------
__global__ __launch_bounds__(256) void attn_kernel(
    const unsigned short* __restrict__ Qp, const unsigned short* __restrict__ Kp,
    const unsigned short* __restrict__ Vt, const int* __restrict__ mask,
    const int* __restrict__ flags, float* __restrict__ attn_out,
    unsigned short* __restrict__ ctx) {
  __shared__ unsigned short Ks[4][64 * 64];  // 32 KB, wave-private 8 KB each
  __shared__ unsigned short Ps[4][64][68];   // 34 KB
  __shared__ float denbuf[2][128];           // 1 KB

  const int tid = threadIdx.x, lane = tid & 63, wid = tid >> 6;
  const int kw = wid & 1, qw = wid >> 1;
  const int l15 = lane & 15, lg = lane >> 4;

  // XCD-aware remap: all 16 q-tiles of a head on one XCD (K/V L2-resident).
  const int wgid = blockIdx.x + gridDim.x * blockIdx.y;  // 0..511
  const int jj = wgid >> 3;
  const int bh = (wgid & 7) * 4 + (jj >> 4);
  const int qt = jj & 15;
  const int q0 = qt * 128;
  const int b = bh >> 4, h = bh & 15;

  const unsigned short* Qh = Qp + (size_t)b * LSEQ * DMOD + h * HDSZ;
  const unsigned short* Kh = Kp + (size_t)b * LSEQ * DMOD + h * HDSZ;
  const unsigned short* Vh = Vt + (size_t)b * DMOD * LSEQ + (size_t)h * HDSZ * LSEQ;
  const int* mb = mask + (size_t)b * LSEQ * LSEQ;
  const int* frow = flags + (b * 16 + qt) * 16;
  float* ah = attn_out + (size_t)bh * LSEQ * LSEQ;

  const int wq0 = q0 + qw * 64;
  const int wk0 = kw * 64;

  short8 qf[4][2];
#pragma unroll
  for (int fq = 0; fq < 4; fq++)
#pragma unroll
    for (int ks = 0; ks < 2; ks++)
      qf[fq][ks] = *(const short8*)(Qh + (size_t)(wq0 + fq * 16 + l15) * DMOD +
                                    ks * 32 + lg * 8);

  // wave-private staging: lane -> row rl8 = lane>>3 (+p*8), chunk jc = lane&7
  unsigned short* Ksw = &Ks[wid][0];
  const int rl8 = lane >> 3, jc = lane & 7;
  const unsigned short* Kwb = Kh + (size_t)(wk0 + rl8) * DMOD + jc * 8;

  // ---------------- sweep 1: denominators (no block barriers) ----------------
  float den[4] = {0.f, 0.f, 0.f, 0.f};
  short8 ka[8];
#pragma unroll
  for (int p = 0; p < 8; p++) ka[p] = *(const short8*)(Kwb + (size_t)(p * 8) * DMOD);

  for (int kt = 0; kt < NT; ++kt) {
#pragma unroll
    for (int p = 0; p < 8; p++) {
      const int r = p * 8 + rl8;
      *(short8*)&Ksw[r * 64 + ((jc ^ (r & 7)) << 3)] = ka[p];
    }
    if (kt + 1 < NT) {
#pragma unroll
      for (int p = 0; p < 8; p++)
        ka[p] = *(const short8*)(Kwb + (size_t)((kt + 1) * 128 + p * 8) * DMOD);
    }
    const bool fast = frow[kt] != 0;
    if (fast) {
#pragma unroll
      for (int fn = 0; fn < 4; fn++) {
        const int krow = fn * 16 + l15;
        const int rb = krow * 64, rx = (krow & 7) << 4;
        short8 kf0 = *(const short8*)&Ksw[rb + (((lg * 16) ^ rx) >> 1)];
        short8 kf1 = *(const short8*)&Ksw[rb + (((64 + lg * 16) ^ rx) >> 1)];
#pragma unroll
        for (int fq = 0; fq < 4; fq++) {
          f32x4 s = (f32x4){0.f, 0.f, 0.f, 0.f};
          s = MFMA16(kf0, qf[fq][0], s);
          s = MFMA16(kf1, qf[fq][1], s);
          den[fq] += EXP2F(s[0]) + EXP2F(s[1]) + EXP2F(s[2]) + EXP2F(s[3]);
        }
      }
    } else {
      const int k0 = kt * 128;
#pragma unroll
      for (int fn = 0; fn < 4; fn++) {
        const int krow = fn * 16 + l15;
        const int rb = krow * 64, rx = (krow & 7) << 4;
        short8 kf0 = *(const short8*)&Ksw[rb + (((lg * 16) ^ rx) >> 1)];
        short8 kf1 = *(const short8*)&Ksw[rb + (((64 + lg * 16) ^ rx) >> 1)];
#pragma unroll
        for (int fq = 0; fq < 4; fq++) {
          const int qrow = wq0 + fq * 16 + l15;
          f32x4 s = (f32x4){0.f, 0.f, 0.f, 0.f};
          s = MFMA16(kf0, qf[fq][0], s);
          s = MFMA16(kf1, qf[fq][1], s);
          i32x4 m4 = *(const i32x4*)(mb + (size_t)qrow * LSEQ + k0 + wk0 + fn * 16 + lg * 4);
          den[fq] += (m4[0] != 0) ? EXP2F(s[0]) : 0.f;
          den[fq] += (m4[1] != 0) ? EXP2F(s[1]) : 0.f;
          den[fq] += (m4[2] != 0) ? EXP2F(s[2]) : 0.f;
          den[fq] += (m4[3] != 0) ? EXP2F(s[3]) : 0.f;
        }
      }
    }
  }
#pragma unroll
  for (int fq = 0; fq < 4; fq++) {
    den[fq] += __shfl_xor(den[fq], 16);
    den[fq] += __shfl_xor(den[fq], 32);
  }
  if (lg == 0) {
#pragma unroll
    for (int fq = 0; fq < 4; fq++) denbuf[kw][qw * 64 + fq * 16 + l15] = den[fq];
  }
  __syncthreads();
  float inv[4];
#pragma unroll
  for (int fq = 0; fq < 4; fq++) {
    const int ql = qw * 64 + fq * 16 + l15;
    inv[fq] = 1.0f / (denbuf[0][ql] + denbuf[1][ql]);
  }

  // ---------------- sweep 2: Ps build + PV + coalesced attn store ----------------
  f32x4 oacc[4][4];
#pragma unroll
  for (int fq = 0; fq < 4; fq++)
#pragma unroll
    for (int fd = 0; fd < 4; fd++) oacc[fq][fd] = (f32x4){0.f, 0.f, 0.f, 0.f};

#pragma unroll
  for (int p = 0; p < 8; p++) ka[p] = *(const short8*)(Kwb + (size_t)(p * 8) * DMOD);

  const unsigned short* Vbase = Vh + (size_t)l15 * LSEQ + wk0 + lg * 8;

  for (int kt = 0; kt < NT; ++kt) {
    const int k0 = kt * 128;
#pragma unroll
    for (int p = 0; p < 8; p++) {
      const int r = p * 8 + rl8;
      *(short8*)&Ksw[r * 64 + ((jc ^ (r & 7)) << 3)] = ka[p];
    }
    if (kt + 1 < NT) {
#pragma unroll
      for (int p = 0; p < 8; p++)
        ka[p] = *(const short8*)(Kwb + (size_t)((kt + 1) * 128 + p * 8) * DMOD);
    }
    short8 vf[4][2];
#pragma unroll
    for (int fd = 0; fd < 4; fd++)
#pragma unroll
      for (int ks = 0; ks < 2; ks++)
        vf[fd][ks] = *(const short8*)(Vbase + (size_t)(fd * 16) * LSEQ + k0 + ks * 32);

    const bool fast = frow[kt] != 0;
    if (fast) {
#pragma unroll
      for (int fn = 0; fn < 4; fn++) {
        const int krow = fn * 16 + l15;
        const int rb = krow * 64, rx = (krow & 7) << 4;
        short8 kf0 = *(const short8*)&Ksw[rb + (((lg * 16) ^ rx) >> 1)];
        short8 kf1 = *(const short8*)&Ksw[rb + (((64 + lg * 16) ^ rx) >> 1)];
#pragma unroll
        for (int fq = 0; fq < 4; fq++) {
          f32x4 s = (f32x4){0.f, 0.f, 0.f, 0.f};
          s = MFMA16(kf0, qf[fq][0], s);
          s = MFMA16(kf1, qf[fq][1], s);
          f32x4 a;
          a[0] = EXP2F(s[0]) * inv[fq];
          a[1] = EXP2F(s[1]) * inv[fq];
          a[2] = EXP2F(s[2]) * inv[fq];
          a[3] = EXP2F(s[3]) * inv[fq];
          union { u16x4 pk; unsigned u[2]; } P;
          P.u[0] = cvt_pk_bf16(a[0], a[1]);
          P.u[1] = cvt_pk_bf16(a[2], a[3]);
          *(u16x4*)&Ps[wid][fq * 16 + l15][fn * 16 + lg * 4] = P.pk;
        }
      }
    } else {
#pragma unroll
      for (int fn = 0; fn < 4; fn++) {
        const int krow = fn * 16 + l15;
        const int rb = krow * 64, rx = (krow & 7) << 4;
        short8 kf0 = *(const short8*)&Ksw[rb + (((lg * 16) ^ rx) >> 1)];
        short8 kf1 = *(const short8*)&Ksw[rb + (((64 + lg * 16) ^ rx) >> 1)];
#pragma unroll
        for (int fq = 0; fq < 4; fq++) {
          const int qrow = wq0 + fq * 16 + l15;
          f32x4 s = (f32x4){0.f, 0.f, 0.f, 0.f};
          s = MFMA16(kf0, qf[fq][0], s);
          s = MFMA16(kf1, qf[fq][1], s);
          i32x4 m4 = *(const i32x4*)(mb + (size_t)qrow * LSEQ + k0 + wk0 + fn * 16 + lg * 4);
          f32x4 a;
          a[0] = (m4[0] != 0) ? EXP2F(s[0]) * inv[fq] : 0.f;
          a[1] = (m4[1] != 0) ? EXP2F(s[1]) * inv[fq] : 0.f;
          a[2] = (m4[2] != 0) ? EXP2F(s[2]) * inv[fq] : 0.f;
          a[3] = (m4[3] != 0) ? EXP2F(s[3]) * inv[fq] : 0.f;
          union { u16x4 pk; unsigned u[2]; } P;
          P.u[0] = cvt_pk_bf16(a[0], a[1]);
          P.u[1] = cvt_pk_bf16(a[2], a[3]);
          *(u16x4*)&Ps[wid][fq * 16 + l15][fn * 16 + lg * 4] = P.pk;
        }
      }
    }
    // PV: A = Ps rows (wave-private), B = V^T rows (registers)
    short8 pa2[4][2];
#pragma unroll
    for (int fq = 0; fq < 4; fq++)
#pragma unroll
      for (int ks = 0; ks < 2; ks++)
        pa2[fq][ks] = *(const short8*)&Ps[wid][fq * 16 + l15][ks * 32 + lg * 8];
#pragma unroll
    for (int fd = 0; fd < 4; fd++) {
#pragma unroll
      for (int fq = 0; fq < 4; fq++) {
        oacc[fq][fd] = MFMA16(pa2[fq][0], vf[fd][0], oacc[fq][fd]);
        oacc[fq][fd] = MFMA16(pa2[fq][1], vf[fd][1], oacc[fq][fd]);
      }
    }
    // coalesced attn store from Ps (bf16 -> fp32): per instruction, 4 rows
    // (i*4+lg) x 256B contiguous segments (16 consecutive-l15 lanes per row).
    {
      float* abase = ah + (size_t)wq0 * LSEQ + k0 + wk0;
#pragma unroll
      for (int i = 0; i < 16; i++) {
        const int qoff = i * 4 + lg;
        unsigned long long d = *(const unsigned long long*)&Ps[wid][qoff][l15 * 4];
        unsigned d0 = (unsigned)d, d1 = (unsigned)(d >> 32);
        union { unsigned u; float f; } t0, t1, t2, t3;
        t0.u = d0 << 16;
        t1.u = d0 & 0xffff0000u;
        t2.u = d1 << 16;
        t3.u = d1 & 0xffff0000u;
        f32x4 a = (f32x4){t0.f, t1.f, t2.f, t3.f};
        __builtin_nontemporal_store(a, (f32x4*)(abase + (size_t)qoff * LSEQ + l15 * 4));
      }
    }
  }

  // ---------------- k-split reduction + ctx store ----------------
  __syncthreads();
  float* red = (float*)&Ps[qw * 2][0][0];
  if (kw == 1) {
#pragma unroll
    for (int fq = 0; fq < 4; fq++)
#pragma unroll
      for (int fd = 0; fd < 4; fd++)
#pragma unroll
        for (int r = 0; r < 4; r++)
          red[(fq * 16 + lg * 4 + r) * 65 + fd * 16 + l15] = oacc[fq][fd][r];
  }
  __syncthreads();
  if (kw == 0) {
    unsigned short* ch = ctx + (size_t)b * LSEQ * DMOD + h * HDSZ;
#pragma unroll
    for (int fq = 0; fq < 4; fq++)
#pragma unroll
      for (int fd = 0; fd < 4; fd++)
#pragma unroll
        for (int r = 0; r < 4; r++) {
          const int qr = wq0 + fq * 16 + lg * 4 + r;
          const float o = oacc[fq][fd][r] + red[(fq * 16 + lg * 4 + r) * 65 + fd * 16 + l15];
          ch[(size_t)qr * DMOD + fd * 16 + l15] = f2bf(o);
        }
  }
}

// ---------------- launcher ----------------
extern "C" void kernel_launch(void* const* d_in, const int* in_sizes, int n_in,
                              void* d_out, int out_size, void* d_ws, size_t ws_size,
                              hipStream_t stream) {
  const float* q = (const float*)d_in[0];
  const float* k = (const float*)d_in[1];
  const float* v = (const float*)d_in[2];
  const int* mask = (const int*)d_in[3];
  const float* Wq = (const float*)d_in[4];
  const float* bq = (const float*)d_in[5];
  const float* Wk = (const float*)d_in[6];
  const float* bk = (const float*)d_in[7];
  const float* Wv = (const float*)d_in[8];
  const float* bv = (const float*)d_in[9];
  const float* Wo = (const float*)d_in[10];
  const float* bo = (const float*)d_in[11];

  float* out = (float*)d_out;
  float* attn = out + (size_t)BSZ * LSEQ * DMOD;

  const size_t NQKV = (size_t)BSZ * LSEQ * DMOD;

  int* flags = (int*)out;  // 512 ints; overwritten by final out-proj

  unsigned short* Qp = (unsigned short*)d_ws;
  unsigned short* Kp = Qp + NQKV;
  unsigned short* Vt = Kp + NQKV;  // (B, D, L)
  unsigned short* ctx = Vt + NQKV;

  // QKV projections (z=0..2) + fused mask-check (z=3, overlaps GEMM).
  // Q scale = 0.125 * log2(e) (exp2-folded softmax).
  gemm_bt<1, 0><<<dim3(32, 8, 4), 256, 0, stream>>>(
      q, k, v, Wq, Wk, Wv, bq, bk, bv, (void*)Qp, (void*)Kp, (void*)Vt,
      0.18033688011112042f, 1.0f, 1.0f, /*vtz=*/2, BSZ * LSEQ, DMOD, DMOD, mask, flags);

  attn_kernel<<<dim3(LSEQ / 128, BSZ * NH), 256, 0, stream>>>(Qp, Kp, Vt, mask, flags,
                                                              attn, ctx);

  gemm_bt<0, 1><<<dim3(32, 8, 1), 256, 0, stream>>>(
      ctx, ctx, ctx, Wo, Wo, Wo, bo, bo, bo, (void*)out, (void*)out, (void*)out,
      1.0f, 1.0f, 1.0f, /*vtz=*/-1, BSZ * LSEQ, DMOD, DMOD, nullptr, nullptr);
}

// Round 14
// 234.890 us; speedup vs baseline: 1.0735x; 1.0735x over previous
//
#include <hip/hip_runtime.h>
#include <stdint.h>

#define BSZ 2
#define LSEQ 2048
#define DMOD 1024
#define NH 16
#define HDSZ 64
#define NT (LSEQ / 128)

typedef __attribute__((ext_vector_type(8))) short short8;
typedef __attribute__((ext_vector_type(4))) float f32x4;
typedef __attribute__((ext_vector_type(4))) unsigned short u16x4;
typedef __attribute__((ext_vector_type(4))) int i32x4;

#define MFMA16(a, b, c) __builtin_amdgcn_mfma_f32_16x16x32_bf16((a), (b), (c), 0, 0, 0)
#define EXP2F(x) __builtin_amdgcn_exp2f(x)

__device__ __forceinline__ unsigned short f2bf(float f) {
  union { float f; unsigned u; } x; x.f = f;
  unsigned u = x.u + 0x7fffu + ((x.u >> 16) & 1u);
  return (unsigned short)(u >> 16);
}

__device__ __forceinline__ unsigned cvt_pk_bf16(float lo, float hi) {
  unsigned r;
  asm("v_cvt_pk_bf16_f32 %0, %1, %2" : "=v"(r) : "v"(lo), "v"(hi));
  return r;
}

__device__ __forceinline__ short8 pack8(f32x4 lo, f32x4 hi) {
  short8 o;
  o[0] = f2bf(lo[0]); o[1] = f2bf(lo[1]); o[2] = f2bf(lo[2]); o[3] = f2bf(lo[3]);
  o[4] = f2bf(hi[0]); o[5] = f2bf(hi[1]); o[6] = f2bf(hi[2]); o[7] = f2bf(hi[3]);
  return o;
}

// ---------------- GEMM: C = A * W^T + bias; z==3 = fused mask-check slice ----------
// (v12 version — reg-staged bf16 LDS; v13's gll fp32 staging regressed.)
template <int AF32, int OUTF32>
__global__ __launch_bounds__(256) void gemm_bt(
    const void* __restrict__ A0, const void* __restrict__ A1, const void* __restrict__ A2,
    const float* __restrict__ W0, const float* __restrict__ W1, const float* __restrict__ W2,
    const float* __restrict__ b0, const float* __restrict__ b1, const float* __restrict__ b2,
    void* __restrict__ C0, void* __restrict__ C1, void* __restrict__ C2,
    float s0, float s1, float s2, int vtz, int M, int N, int K,
    const int* __restrict__ mask, int* __restrict__ flags) {
  const int z = blockIdx.z;
  const int tid = threadIdx.x;
  __shared__ int red[4];

  if (z == 3) {
    const int t0 = (blockIdx.x + 32 * blockIdx.y) * 2;
#pragma unroll
    for (int t = t0; t < t0 + 2; ++t) {
      const int b_ = t >> 8, qt = (t >> 4) & 15, ktt = t & 15;
      const int r = tid >> 1, c = (tid & 1) * 64;
      const int* mr = mask + (size_t)b_ * LSEQ * LSEQ + (size_t)(qt * 128 + r) * LSEQ +
                      ktt * 128 + c;
      int ok = 1;
#pragma unroll
      for (int j = 0; j < 16; j++) {
        i32x4 v = __builtin_nontemporal_load((const i32x4*)(mr + j * 4));
        ok &= (v[0] != 0) & (v[1] != 0) & (v[2] != 0) & (v[3] != 0);
      }
      unsigned long long vote = __ballot(ok);
      if ((tid & 63) == 0) red[tid >> 6] = (vote == ~0ull) ? 1 : 0;
      __syncthreads();
      if (tid == 0) flags[(b_ * 16 + qt) * 16 + ktt] = red[0] & red[1] & red[2] & red[3];
      __syncthreads();
    }
    return;
  }

  const void* A = (z == 0) ? A0 : ((z == 1) ? A1 : A2);
  const float* W = (z == 0) ? W0 : ((z == 1) ? W1 : W2);
  const float* bias = (z == 0) ? b0 : ((z == 1) ? b1 : b2);
  void* Cout = (z == 0) ? C0 : ((z == 1) ? C1 : C2);
  const float scale = (z == 0) ? s0 : ((z == 1) ? s1 : s2);

  __shared__ unsigned short As[128 * 40];
  __shared__ unsigned short Bs[128 * 40];

  const int lane = tid & 63;
  const int wid = tid >> 6;
  const int bm = blockIdx.x, bn = blockIdx.y;
  const int wm = (wid >> 1) * 64, wn = (wid & 1) * 64;

  f32x4 acc[4][4];
#pragma unroll
  for (int i = 0; i < 4; i++)
#pragma unroll
    for (int j = 0; j < 4; j++) acc[i][j] = (f32x4){0.f, 0.f, 0.f, 0.f};

  const int r0 = tid >> 2;
  const int c0 = (tid & 3) * 8;
  const float* Wg = W + (size_t)(bn * 128 + r0) * K + c0;

  f32x4 vaf[2][2], vbf[2][2];
  short8 vah[2];
  if constexpr (AF32) {
    const float* Ag = (const float*)A + (size_t)(bm * 128 + r0) * K + c0;
#pragma unroll
    for (int j = 0; j < 2; j++) {
      vaf[j][0] = *(const f32x4*)(Ag + (size_t)(j * 64) * K);
      vaf[j][1] = *(const f32x4*)(Ag + (size_t)(j * 64) * K + 4);
    }
  } else {
    const unsigned short* Ag = (const unsigned short*)A + (size_t)(bm * 128 + r0) * K + c0;
#pragma unroll
    for (int j = 0; j < 2; j++) vah[j] = *(const short8*)(Ag + (size_t)(j * 64) * K);
  }
#pragma unroll
  for (int j = 0; j < 2; j++) {
    vbf[j][0] = *(const f32x4*)(Wg + (size_t)(j * 64) * K);
    vbf[j][1] = *(const f32x4*)(Wg + (size_t)(j * 64) * K + 4);
  }

  for (int k0 = 0; k0 < K; k0 += 32) {
#pragma unroll
    for (int j = 0; j < 2; j++) {
      if constexpr (AF32)
        *(short8*)&As[(j * 64 + r0) * 40 + c0] = pack8(vaf[j][0], vaf[j][1]);
      else
        *(short8*)&As[(j * 64 + r0) * 40 + c0] = vah[j];
      *(short8*)&Bs[(j * 64 + r0) * 40 + c0] = pack8(vbf[j][0], vbf[j][1]);
    }
    __syncthreads();
    if (k0 + 32 < K) {
      if constexpr (AF32) {
        const float* Ag = (const float*)A + (size_t)(bm * 128 + r0) * K + c0 + k0 + 32;
#pragma unroll
        for (int j = 0; j < 2; j++) {
          vaf[j][0] = *(const f32x4*)(Ag + (size_t)(j * 64) * K);
          vaf[j][1] = *(const f32x4*)(Ag + (size_t)(j * 64) * K + 4);
        }
      } else {
        const unsigned short* Ag =
            (const unsigned short*)A + (size_t)(bm * 128 + r0) * K + c0 + k0 + 32;
#pragma unroll
        for (int j = 0; j < 2; j++) vah[j] = *(const short8*)(Ag + (size_t)(j * 64) * K);
      }
#pragma unroll
      for (int j = 0; j < 2; j++) {
        vbf[j][0] = *(const f32x4*)(Wg + (size_t)(j * 64) * K + k0 + 32);
        vbf[j][1] = *(const f32x4*)(Wg + (size_t)(j * 64) * K + k0 + 36);
      }
    }
    short8 af[4], bf[4];
#pragma unroll
    for (int i = 0; i < 4; i++)
      af[i] = *(const short8*)&As[(wm + i * 16 + (lane & 15)) * 40 + (lane >> 4) * 8];
#pragma unroll
    for (int i = 0; i < 4; i++)
      bf[i] = *(const short8*)&Bs[(wn + i * 16 + (lane & 15)) * 40 + (lane >> 4) * 8];
#pragma unroll
    for (int i = 0; i < 4; i++)
#pragma unroll
      for (int j = 0; j < 4; j++) acc[i][j] = MFMA16(af[i], bf[j], acc[i][j]);
    __syncthreads();
  }

  const bool vtrans = (z == vtz);
  const int crow = bm * 128 + wm + ((lane >> 4) & 3) * 4;
#pragma unroll
  for (int j = 0; j < 4; j++) {
    const int col = bn * 128 + wn + j * 16 + (lane & 15);
    const float bv = bias[col];
#pragma unroll
    for (int i = 0; i < 4; i++) {
      if (OUTF32) {
#pragma unroll
        for (int r = 0; r < 4; r++) {
          float vvv = (acc[i][j][r] + bv) * scale;
          ((float*)Cout)[(size_t)(crow + i * 16 + r) * N + col] = vvv;
        }
      } else if (vtrans) {
        u16x4 pk;
#pragma unroll
        for (int r = 0; r < 4; r++) pk[r] = f2bf((acc[i][j][r] + bv) * scale);
        const int row = crow + i * 16;
        unsigned short* dst = (unsigned short*)Cout +
                              (size_t)(row >> 11) * DMOD * LSEQ + (size_t)col * LSEQ +
                              (row & (LSEQ - 1));
        *(u16x4*)dst = pk;
      } else {
#pragma unroll
        for (int r = 0; r < 4; r++) {
          float vvv = (acc[i][j][r] + bv) * scale;
          ((unsigned short*)Cout)[(size_t)(crow + i * 16 + r) * N + col] = f2bf(vvv);
        }
      }
    }
  }
}

// ---------------- fused attention (v14: q-only wave split, 512B store segments) -----
// 4 waves x 32 q-rows, each wave covers the FULL 128-k tile:
//  - attn store readback emits 512B contiguous segments (2 full rows / instr)
//  - no k-split: den is intra-wave (shuffle only), oacc stored directly
//  - K staged in shared LDS (16 KB, XOR swizzle, 2 barriers/tile — v6-proven)
__global__ __launch_bounds__(256) void attn_kernel(
    const unsigned short* __restrict__ Qp, const unsigned short* __restrict__ Kp,
    const unsigned short* __restrict__ Vt, const int* __restrict__ mask,
    const int* __restrict__ flags, float* __restrict__ attn_out,
    unsigned short* __restrict__ ctx) {
  __shared__ unsigned short Ks[128 * 64];    // 16 KB, XOR-swizzled
  __shared__ unsigned short Ps[4][32][136];  // 34 KB (136: 16B-aligned rows)

  const int tid = threadIdx.x, lane = tid & 63, wid = tid >> 6;
  const int l15 = lane & 15, lg = lane >> 4;

  // XCD-aware remap: all 16 q-tiles of a head on one XCD (K/V L2-resident).
  const int wgid = blockIdx.x + gridDim.x * blockIdx.y;  // 0..511
  const int jj = wgid >> 3;
  const int bh = (wgid & 7) * 4 + (jj >> 4);
  const int qt = jj & 15;
  const int q0 = qt * 128;
  const int b = bh >> 4, h = bh & 15;

  const unsigned short* Qh = Qp + (size_t)b * LSEQ * DMOD + h * HDSZ;
  const unsigned short* Kh = Kp + (size_t)b * LSEQ * DMOD + h * HDSZ;
  const unsigned short* Vh = Vt + (size_t)b * DMOD * LSEQ + (size_t)h * HDSZ * LSEQ;
  const int* mb = mask + (size_t)b * LSEQ * LSEQ;
  const int* frow = flags + (b * 16 + qt) * 16;
  float* ah = attn_out + (size_t)bh * LSEQ * LSEQ;

  const int wq0 = q0 + wid * 32;  // wave's 32 q-rows

  short8 qf[2][2];
#pragma unroll
  for (int fq = 0; fq < 2; fq++)
#pragma unroll
    for (int ks = 0; ks < 2; ks++)
      qf[fq][ks] = *(const short8*)(Qh + (size_t)(wq0 + fq * 16 + l15) * DMOD +
                                    ks * 32 + lg * 8);

  // shared K staging (v6 pattern): thread -> row sr, 64B half, 4x16B chunks
  const int sr = tid >> 1;
  const unsigned short* Kst = Kh + (size_t)sr * DMOD + (tid & 1) * 32;
  const int swz_w = (sr & 7) << 4;

  // ---------------- sweep 1: denominators ----------------
  float den[2] = {0.f, 0.f};
  short8 ka[4];
#pragma unroll
  for (int j = 0; j < 4; j++) ka[j] = *(const short8*)(Kst + j * 8);

  for (int kt = 0; kt < NT; ++kt) {
    __syncthreads();
#pragma unroll
    for (int j = 0; j < 4; j++)
      *(short8*)&Ks[sr * 64 + (((((tid & 1) * 64) + j * 16) ^ swz_w) >> 1)] = ka[j];
    __syncthreads();
    if (kt + 1 < NT) {
#pragma unroll
      for (int j = 0; j < 4; j++)
        ka[j] = *(const short8*)(Kst + (size_t)(kt + 1) * 128 * DMOD + j * 8);
    }
    const bool fast = frow[kt] != 0;
    if (fast) {
#pragma unroll
      for (int fn = 0; fn < 8; fn++) {
        const int krow = fn * 16 + l15;
        const int rb = krow * 64, rx = (krow & 7) << 4;
        short8 kf0 = *(const short8*)&Ks[rb + (((lg * 16) ^ rx) >> 1)];
        short8 kf1 = *(const short8*)&Ks[rb + (((64 + lg * 16) ^ rx) >> 1)];
#pragma unroll
        for (int fq = 0; fq < 2; fq++) {
          f32x4 s = (f32x4){0.f, 0.f, 0.f, 0.f};
          s = MFMA16(kf0, qf[fq][0], s);
          s = MFMA16(kf1, qf[fq][1], s);
          den[fq] += EXP2F(s[0]) + EXP2F(s[1]) + EXP2F(s[2]) + EXP2F(s[3]);
        }
      }
    } else {
      const int k0 = kt * 128;
#pragma unroll
      for (int fn = 0; fn < 8; fn++) {
        const int krow = fn * 16 + l15;
        const int rb = krow * 64, rx = (krow & 7) << 4;
        short8 kf0 = *(const short8*)&Ks[rb + (((lg * 16) ^ rx) >> 1)];
        short8 kf1 = *(const short8*)&Ks[rb + (((64 + lg * 16) ^ rx) >> 1)];
#pragma unroll
        for (int fq = 0; fq < 2; fq++) {
          const int qrow = wq0 + fq * 16 + l15;
          f32x4 s = (f32x4){0.f, 0.f, 0.f, 0.f};
          s = MFMA16(kf0, qf[fq][0], s);
          s = MFMA16(kf1, qf[fq][1], s);
          i32x4 m4 = *(const i32x4*)(mb + (size_t)qrow * LSEQ + k0 + fn * 16 + lg * 4);
          den[fq] += (m4[0] != 0) ? EXP2F(s[0]) : 0.f;
          den[fq] += (m4[1] != 0) ? EXP2F(s[1]) : 0.f;
          den[fq] += (m4[2] != 0) ? EXP2F(s[2]) : 0.f;
          den[fq] += (m4[3] != 0) ? EXP2F(s[3]) : 0.f;
        }
      }
    }
  }
  float inv[2];
#pragma unroll
  for (int fq = 0; fq < 2; fq++) {
    den[fq] += __shfl_xor(den[fq], 16);
    den[fq] += __shfl_xor(den[fq], 32);
    inv[fq] = 1.0f / den[fq];
  }

  // ---------------- sweep 2: Ps build + PV + 512B coalesced attn store ----------
  f32x4 oacc[2][4];
#pragma unroll
  for (int fq = 0; fq < 2; fq++)
#pragma unroll
    for (int fd = 0; fd < 4; fd++) oacc[fq][fd] = (f32x4){0.f, 0.f, 0.f, 0.f};

#pragma unroll
  for (int j = 0; j < 4; j++) ka[j] = *(const short8*)(Kst + j * 8);

  const unsigned short* Vbase = Vh + (size_t)l15 * LSEQ + lg * 8;

  for (int kt = 0; kt < NT; ++kt) {
    const int k0 = kt * 128;
    __syncthreads();
#pragma unroll
    for (int j = 0; j < 4; j++)
      *(short8*)&Ks[sr * 64 + (((((tid & 1) * 64) + j * 16) ^ swz_w) >> 1)] = ka[j];
    __syncthreads();
    if (kt + 1 < NT) {
#pragma unroll
      for (int j = 0; j < 4; j++)
        ka[j] = *(const short8*)(Kst + (size_t)(kt + 1) * 128 * DMOD + j * 8);
    }
    short8 vf[4][4];
#pragma unroll
    for (int fd = 0; fd < 4; fd++)
#pragma unroll
      for (int ks = 0; ks < 4; ks++)
        vf[fd][ks] = *(const short8*)(Vbase + (size_t)(fd * 16) * LSEQ + k0 + ks * 32);

    const bool fast = frow[kt] != 0;
    if (fast) {
#pragma unroll
      for (int fn = 0; fn < 8; fn++) {
        const int krow = fn * 16 + l15;
        const int rb = krow * 64, rx = (krow & 7) << 4;
        short8 kf0 = *(const short8*)&Ks[rb + (((lg * 16) ^ rx) >> 1)];
        short8 kf1 = *(const short8*)&Ks[rb + (((64 + lg * 16) ^ rx) >> 1)];
#pragma unroll
        for (int fq = 0; fq < 2; fq++) {
          f32x4 s = (f32x4){0.f, 0.f, 0.f, 0.f};
          s = MFMA16(kf0, qf[fq][0], s);
          s = MFMA16(kf1, qf[fq][1], s);
          f32x4 a;
          a[0] = EXP2F(s[0]) * inv[fq];
          a[1] = EXP2F(s[1]) * inv[fq];
          a[2] = EXP2F(s[2]) * inv[fq];
          a[3] = EXP2F(s[3]) * inv[fq];
          union { u16x4 pk; unsigned u[2]; } P;
          P.u[0] = cvt_pk_bf16(a[0], a[1]);
          P.u[1] = cvt_pk_bf16(a[2], a[3]);
          *(u16x4*)&Ps[wid][fq * 16 + l15][fn * 16 + lg * 4] = P.pk;
        }
      }
    } else {
#pragma unroll
      for (int fn = 0; fn < 8; fn++) {
        const int krow = fn * 16 + l15;
        const int rb = krow * 64, rx = (krow & 7) << 4;
        short8 kf0 = *(const short8*)&Ks[rb + (((lg * 16) ^ rx) >> 1)];
        short8 kf1 = *(const short8*)&Ks[rb + (((64 + lg * 16) ^ rx) >> 1)];
#pragma unroll
        for (int fq = 0; fq < 2; fq++) {
          const int qrow = wq0 + fq * 16 + l15;
          f32x4 s = (f32x4){0.f, 0.f, 0.f, 0.f};
          s = MFMA16(kf0, qf[fq][0], s);
          s = MFMA16(kf1, qf[fq][1], s);
          i32x4 m4 = *(const i32x4*)(mb + (size_t)qrow * LSEQ + k0 + fn * 16 + lg * 4);
          f32x4 a;
          a[0] = (m4[0] != 0) ? EXP2F(s[0]) * inv[fq] : 0.f;
          a[1] = (m4[1] != 0) ? EXP2F(s[1]) * inv[fq] : 0.f;
          a[2] = (m4[2] != 0) ? EXP2F(s[2]) * inv[fq] : 0.f;
          a[3] = (m4[3] != 0) ? EXP2F(s[3]) * inv[fq] : 0.f;
          union { u16x4 pk; unsigned u[2]; } P;
          P.u[0] = cvt_pk_bf16(a[0], a[1]);
          P.u[1] = cvt_pk_bf16(a[2], a[3]);
          *(u16x4*)&Ps[wid][fq * 16 + l15][fn * 16 + lg * 4] = P.pk;
        }
      }
    }
    // PV: A = Ps rows (wave-private), B = V^T rows (registers); full 128-k
    short8 pa2[2][4];
#pragma unroll
    for (int fq = 0; fq < 2; fq++)
#pragma unroll
      for (int ks = 0; ks < 4; ks++)
        pa2[fq][ks] = *(const short8*)&Ps[wid][fq * 16 + l15][ks * 32 + lg * 8];
#pragma unroll
    for (int fd = 0; fd < 4; fd++)
#pragma unroll
      for (int fq = 0; fq < 2; fq++)
#pragma unroll
        for (int ks = 0; ks < 4; ks++)
          oacc[fq][fd] = MFMA16(pa2[fq][ks], vf[fd][ks], oacc[fq][fd]);

    // coalesced attn store: per instruction, 2 full rows x 512B contiguous
    {
      float* abase = ah + (size_t)wq0 * LSEQ + k0;
      const int rsel = lane >> 5, csel = (lane & 31) * 4;
#pragma unroll
      for (int i = 0; i < 16; i++) {
        const int qoff = i * 2 + rsel;
        unsigned long long d = *(const unsigned long long*)&Ps[wid][qoff][csel];
        unsigned d0 = (unsigned)d, d1 = (unsigned)(d >> 32);
        union { unsigned u; float f; } t0, t1, t2, t3;
        t0.u = d0 << 16;
        t1.u = d0 & 0xffff0000u;
        t2.u = d1 << 16;
        t3.u = d1 & 0xffff0000u;
        f32x4 a = (f32x4){t0.f, t1.f, t2.f, t3.f};
        __builtin_nontemporal_store(a, (f32x4*)(abase + (size_t)qoff * LSEQ + csel));
      }
    }
  }

  // ---------------- ctx store (no k-split reduction needed) ----------------
  unsigned short* ch = ctx + (size_t)b * LSEQ * DMOD + h * HDSZ;
#pragma unroll
  for (int fq = 0; fq < 2; fq++)
#pragma unroll
    for (int fd = 0; fd < 4; fd++)
#pragma unroll
      for (int r = 0; r < 4; r++) {
        const int qr = wq0 + fq * 16 + lg * 4 + r;
        ch[(size_t)qr * DMOD + fd * 16 + l15] = f2bf(oacc[fq][fd][r]);
      }
}

// ---------------- launcher ----------------
extern "C" void kernel_launch(void* const* d_in, const int* in_sizes, int n_in,
                              void* d_out, int out_size, void* d_ws, size_t ws_size,
                              hipStream_t stream) {
  const float* q = (const float*)d_in[0];
  const float* k = (const float*)d_in[1];
  const float* v = (const float*)d_in[2];
  const int* mask = (const int*)d_in[3];
  const float* Wq = (const float*)d_in[4];
  const float* bq = (const float*)d_in[5];
  const float* Wk = (const float*)d_in[6];
  const float* bk = (const float*)d_in[7];
  const float* Wv = (const float*)d_in[8];
  const float* bv = (const float*)d_in[9];
  const float* Wo = (const float*)d_in[10];
  const float* bo = (const float*)d_in[11];

  float* out = (float*)d_out;
  float* attn = out + (size_t)BSZ * LSEQ * DMOD;

  const size_t NQKV = (size_t)BSZ * LSEQ * DMOD;

  int* flags = (int*)out;  // 512 ints; overwritten by final out-proj

  unsigned short* Qp = (unsigned short*)d_ws;
  unsigned short* Kp = Qp + NQKV;
  unsigned short* Vt = Kp + NQKV;  // (B, D, L)
  unsigned short* ctx = Vt + NQKV;

  // QKV projections (z=0..2) + fused mask-check (z=3, overlaps GEMM).
  // Q scale = 0.125 * log2(e) (exp2-folded softmax).
  gemm_bt<1, 0><<<dim3(32, 8, 4), 256, 0, stream>>>(
      q, k, v, Wq, Wk, Wv, bq, bk, bv, (void*)Qp, (void*)Kp, (void*)Vt,
      0.18033688011112042f, 1.0f, 1.0f, /*vtz=*/2, BSZ * LSEQ, DMOD, DMOD, mask, flags);

  attn_kernel<<<dim3(LSEQ / 128, BSZ * NH), 256, 0, stream>>>(Qp, Kp, Vt, mask, flags,
                                                              attn, ctx);

  gemm_bt<0, 1><<<dim3(32, 8, 1), 256, 0, stream>>>(
      ctx, ctx, ctx, Wo, Wo, Wo, bo, bo, bo, (void*)out, (void*)out, (void*)out,
      1.0f, 1.0f, 1.0f, /*vtz=*/-1, BSZ * LSEQ, DMOD, DMOD, nullptr, nullptr);
}

// Round 15
// 228.903 us; speedup vs baseline: 1.1016x; 1.0262x over previous
//
#include <hip/hip_runtime.h>
#include <stdint.h>

#define BSZ 2
#define LSEQ 2048
#define DMOD 1024
#define NH 16
#define HDSZ 64
#define NT (LSEQ / 128)

typedef __attribute__((ext_vector_type(8))) short short8;
typedef __attribute__((ext_vector_type(4))) float f32x4;
typedef __attribute__((ext_vector_type(4))) unsigned short u16x4;
typedef __attribute__((ext_vector_type(4))) int i32x4;

#define MFMA16(a, b, c) __builtin_amdgcn_mfma_f32_16x16x32_bf16((a), (b), (c), 0, 0, 0)
#define EXP2F(x) __builtin_amdgcn_exp2f(x)

__device__ __forceinline__ unsigned short f2bf(float f) {
  union { float f; unsigned u; } x; x.f = f;
  unsigned u = x.u + 0x7fffu + ((x.u >> 16) & 1u);
  return (unsigned short)(u >> 16);
}

__device__ __forceinline__ unsigned cvt_pk_bf16(float lo, float hi) {
  unsigned r;
  asm("v_cvt_pk_bf16_f32 %0, %1, %2" : "=v"(r) : "v"(lo), "v"(hi));
  return r;
}

// packed RNE fp32->bf16 x8 via v_cvt_pk (4 instructions)
__device__ __forceinline__ short8 pack8_pk(f32x4 lo, f32x4 hi) {
  union { short8 s; unsigned u[4]; } r;
  r.u[0] = cvt_pk_bf16(lo[0], lo[1]);
  r.u[1] = cvt_pk_bf16(lo[2], lo[3]);
  r.u[2] = cvt_pk_bf16(hi[0], hi[1]);
  r.u[3] = cvt_pk_bf16(hi[2], hi[3]);
  return r.s;
}

__device__ __forceinline__ u16x4 pack4_pk(float a, float b, float c, float d) {
  union { u16x4 p; unsigned u[2]; } r;
  r.u[0] = cvt_pk_bf16(a, b);
  r.u[1] = cvt_pk_bf16(c, d);
  return r.p;
}

// ---------------- GEMM: C = A * W^T + bias; z==3 = fused mask-check slice ----------
// v15: v12 structure with ALL fp32->bf16 packing via v_cvt_pk_bf16_f32.
template <int AF32, int OUTF32>
__global__ __launch_bounds__(256) void gemm_bt(
    const void* __restrict__ A0, const void* __restrict__ A1, const void* __restrict__ A2,
    const float* __restrict__ W0, const float* __restrict__ W1, const float* __restrict__ W2,
    const float* __restrict__ b0, const float* __restrict__ b1, const float* __restrict__ b2,
    void* __restrict__ C0, void* __restrict__ C1, void* __restrict__ C2,
    float s0, float s1, float s2, int vtz, int M, int N, int K,
    const int* __restrict__ mask, int* __restrict__ flags) {
  const int z = blockIdx.z;
  const int tid = threadIdx.x;
  __shared__ int red[4];

  if (z == 3) {
    const int t0 = (blockIdx.x + 32 * blockIdx.y) * 2;
#pragma unroll
    for (int t = t0; t < t0 + 2; ++t) {
      const int b_ = t >> 8, qt = (t >> 4) & 15, ktt = t & 15;
      const int r = tid >> 1, c = (tid & 1) * 64;
      const int* mr = mask + (size_t)b_ * LSEQ * LSEQ + (size_t)(qt * 128 + r) * LSEQ +
                      ktt * 128 + c;
      int ok = 1;
#pragma unroll
      for (int j = 0; j < 16; j++) {
        i32x4 v = __builtin_nontemporal_load((const i32x4*)(mr + j * 4));
        ok &= (v[0] != 0) & (v[1] != 0) & (v[2] != 0) & (v[3] != 0);
      }
      unsigned long long vote = __ballot(ok);
      if ((tid & 63) == 0) red[tid >> 6] = (vote == ~0ull) ? 1 : 0;
      __syncthreads();
      if (tid == 0) flags[(b_ * 16 + qt) * 16 + ktt] = red[0] & red[1] & red[2] & red[3];
      __syncthreads();
    }
    return;
  }

  const void* A = (z == 0) ? A0 : ((z == 1) ? A1 : A2);
  const float* W = (z == 0) ? W0 : ((z == 1) ? W1 : W2);
  const float* bias = (z == 0) ? b0 : ((z == 1) ? b1 : b2);
  void* Cout = (z == 0) ? C0 : ((z == 1) ? C1 : C2);
  const float scale = (z == 0) ? s0 : ((z == 1) ? s1 : s2);

  __shared__ unsigned short As[128 * 40];
  __shared__ unsigned short Bs[128 * 40];

  const int lane = tid & 63;
  const int wid = tid >> 6;
  const int bm = blockIdx.x, bn = blockIdx.y;
  const int wm = (wid >> 1) * 64, wn = (wid & 1) * 64;

  f32x4 acc[4][4];
#pragma unroll
  for (int i = 0; i < 4; i++)
#pragma unroll
    for (int j = 0; j < 4; j++) acc[i][j] = (f32x4){0.f, 0.f, 0.f, 0.f};

  const int r0 = tid >> 2;
  const int c0 = (tid & 3) * 8;
  const float* Wg = W + (size_t)(bn * 128 + r0) * K + c0;

  f32x4 vaf[2][2], vbf[2][2];
  short8 vah[2];
  if constexpr (AF32) {
    const float* Ag = (const float*)A + (size_t)(bm * 128 + r0) * K + c0;
#pragma unroll
    for (int j = 0; j < 2; j++) {
      vaf[j][0] = *(const f32x4*)(Ag + (size_t)(j * 64) * K);
      vaf[j][1] = *(const f32x4*)(Ag + (size_t)(j * 64) * K + 4);
    }
  } else {
    const unsigned short* Ag = (const unsigned short*)A + (size_t)(bm * 128 + r0) * K + c0;
#pragma unroll
    for (int j = 0; j < 2; j++) vah[j] = *(const short8*)(Ag + (size_t)(j * 64) * K);
  }
#pragma unroll
  for (int j = 0; j < 2; j++) {
    vbf[j][0] = *(const f32x4*)(Wg + (size_t)(j * 64) * K);
    vbf[j][1] = *(const f32x4*)(Wg + (size_t)(j * 64) * K + 4);
  }

  for (int k0 = 0; k0 < K; k0 += 32) {
#pragma unroll
    for (int j = 0; j < 2; j++) {
      if constexpr (AF32)
        *(short8*)&As[(j * 64 + r0) * 40 + c0] = pack8_pk(vaf[j][0], vaf[j][1]);
      else
        *(short8*)&As[(j * 64 + r0) * 40 + c0] = vah[j];
      *(short8*)&Bs[(j * 64 + r0) * 40 + c0] = pack8_pk(vbf[j][0], vbf[j][1]);
    }
    __syncthreads();
    if (k0 + 32 < K) {
      if constexpr (AF32) {
        const float* Ag = (const float*)A + (size_t)(bm * 128 + r0) * K + c0 + k0 + 32;
#pragma unroll
        for (int j = 0; j < 2; j++) {
          vaf[j][0] = *(const f32x4*)(Ag + (size_t)(j * 64) * K);
          vaf[j][1] = *(const f32x4*)(Ag + (size_t)(j * 64) * K + 4);
        }
      } else {
        const unsigned short* Ag =
            (const unsigned short*)A + (size_t)(bm * 128 + r0) * K + c0 + k0 + 32;
#pragma unroll
        for (int j = 0; j < 2; j++) vah[j] = *(const short8*)(Ag + (size_t)(j * 64) * K);
      }
#pragma unroll
      for (int j = 0; j < 2; j++) {
        vbf[j][0] = *(const f32x4*)(Wg + (size_t)(j * 64) * K + k0 + 32);
        vbf[j][1] = *(const f32x4*)(Wg + (size_t)(j * 64) * K + k0 + 36);
      }
    }
    short8 af[4], bf[4];
#pragma unroll
    for (int i = 0; i < 4; i++)
      af[i] = *(const short8*)&As[(wm + i * 16 + (lane & 15)) * 40 + (lane >> 4) * 8];
#pragma unroll
    for (int i = 0; i < 4; i++)
      bf[i] = *(const short8*)&Bs[(wn + i * 16 + (lane & 15)) * 40 + (lane >> 4) * 8];
#pragma unroll
    for (int i = 0; i < 4; i++)
#pragma unroll
      for (int j = 0; j < 4; j++) acc[i][j] = MFMA16(af[i], bf[j], acc[i][j]);
    __syncthreads();
  }

  const bool vtrans = (z == vtz);
  const int crow = bm * 128 + wm + ((lane >> 4) & 3) * 4;
#pragma unroll
  for (int j = 0; j < 4; j++) {
    const int col = bn * 128 + wn + j * 16 + (lane & 15);
    const float bv = bias[col];
#pragma unroll
    for (int i = 0; i < 4; i++) {
      if (OUTF32) {
#pragma unroll
        for (int r = 0; r < 4; r++) {
          float vvv = (acc[i][j][r] + bv) * scale;
          ((float*)Cout)[(size_t)(crow + i * 16 + r) * N + col] = vvv;
        }
      } else if (vtrans) {
        u16x4 pk = pack4_pk((acc[i][j][0] + bv) * scale, (acc[i][j][1] + bv) * scale,
                            (acc[i][j][2] + bv) * scale, (acc[i][j][3] + bv) * scale);
        const int row = crow + i * 16;
        unsigned short* dst = (unsigned short*)Cout +
                              (size_t)(row >> 11) * DMOD * LSEQ + (size_t)col * LSEQ +
                              (row & (LSEQ - 1));
        *(u16x4*)dst = pk;
      } else {
#pragma unroll
        for (int r = 0; r < 4; r++) {
          float vvv = (acc[i][j][r] + bv) * scale;
          ((unsigned short*)Cout)[(size_t)(crow + i * 16 + r) * N + col] =
              (unsigned short)(cvt_pk_bf16(vvv, vvv) & 0xffffu);
        }
      }
    }
  }
}

// ---------------- fused attention (v14: q-only wave split, 512B store segments) -----
__global__ __launch_bounds__(256) void attn_kernel(
    const unsigned short* __restrict__ Qp, const unsigned short* __restrict__ Kp,
    const unsigned short* __restrict__ Vt, const int* __restrict__ mask,
    const int* __restrict__ flags, float* __restrict__ attn_out,
    unsigned short* __restrict__ ctx) {
  __shared__ unsigned short Ks[128 * 64];    // 16 KB, XOR-swizzled
  __shared__ unsigned short Ps[4][32][136];  // 34 KB (136: 16B-aligned rows)

  const int tid = threadIdx.x, lane = tid & 63, wid = tid >> 6;
  const int l15 = lane & 15, lg = lane >> 4;

  // XCD-aware remap: all 16 q-tiles of a head on one XCD (K/V L2-resident).
  const int wgid = blockIdx.x + gridDim.x * blockIdx.y;  // 0..511
  const int jj = wgid >> 3;
  const int bh = (wgid & 7) * 4 + (jj >> 4);
  const int qt = jj & 15;
  const int q0 = qt * 128;
  const int b = bh >> 4, h = bh & 15;

  const unsigned short* Qh = Qp + (size_t)b * LSEQ * DMOD + h * HDSZ;
  const unsigned short* Kh = Kp + (size_t)b * LSEQ * DMOD + h * HDSZ;
  const unsigned short* Vh = Vt + (size_t)b * DMOD * LSEQ + (size_t)h * HDSZ * LSEQ;
  const int* mb = mask + (size_t)b * LSEQ * LSEQ;
  const int* frow = flags + (b * 16 + qt) * 16;
  float* ah = attn_out + (size_t)bh * LSEQ * LSEQ;

  const int wq0 = q0 + wid * 32;  // wave's 32 q-rows

  short8 qf[2][2];
#pragma unroll
  for (int fq = 0; fq < 2; fq++)
#pragma unroll
    for (int ks = 0; ks < 2; ks++)
      qf[fq][ks] = *(const short8*)(Qh + (size_t)(wq0 + fq * 16 + l15) * DMOD +
                                    ks * 32 + lg * 8);

  // shared K staging (v6 pattern): thread -> row sr, 64B half, 4x16B chunks
  const int sr = tid >> 1;
  const unsigned short* Kst = Kh + (size_t)sr * DMOD + (tid & 1) * 32;
  const int swz_w = (sr & 7) << 4;

  // ---------------- sweep 1: denominators ----------------
  float den[2] = {0.f, 0.f};
  short8 ka[4];
#pragma unroll
  for (int j = 0; j < 4; j++) ka[j] = *(const short8*)(Kst + j * 8);

  for (int kt = 0; kt < NT; ++kt) {
    __syncthreads();
#pragma unroll
    for (int j = 0; j < 4; j++)
      *(short8*)&Ks[sr * 64 + (((((tid & 1) * 64) + j * 16) ^ swz_w) >> 1)] = ka[j];
    __syncthreads();
    if (kt + 1 < NT) {
#pragma unroll
      for (int j = 0; j < 4; j++)
        ka[j] = *(const short8*)(Kst + (size_t)(kt + 1) * 128 * DMOD + j * 8);
    }
    const bool fast = frow[kt] != 0;
    if (fast) {
#pragma unroll
      for (int fn = 0; fn < 8; fn++) {
        const int krow = fn * 16 + l15;
        const int rb = krow * 64, rx = (krow & 7) << 4;
        short8 kf0 = *(const short8*)&Ks[rb + (((lg * 16) ^ rx) >> 1)];
        short8 kf1 = *(const short8*)&Ks[rb + (((64 + lg * 16) ^ rx) >> 1)];
#pragma unroll
        for (int fq = 0; fq < 2; fq++) {
          f32x4 s = (f32x4){0.f, 0.f, 0.f, 0.f};
          s = MFMA16(kf0, qf[fq][0], s);
          s = MFMA16(kf1, qf[fq][1], s);
          den[fq] += EXP2F(s[0]) + EXP2F(s[1]) + EXP2F(s[2]) + EXP2F(s[3]);
        }
      }
    } else {
      const int k0 = kt * 128;
#pragma unroll
      for (int fn = 0; fn < 8; fn++) {
        const int krow = fn * 16 + l15;
        const int rb = krow * 64, rx = (krow & 7) << 4;
        short8 kf0 = *(const short8*)&Ks[rb + (((lg * 16) ^ rx) >> 1)];
        short8 kf1 = *(const short8*)&Ks[rb + (((64 + lg * 16) ^ rx) >> 1)];
#pragma unroll
        for (int fq = 0; fq < 2; fq++) {
          const int qrow = wq0 + fq * 16 + l15;
          f32x4 s = (f32x4){0.f, 0.f, 0.f, 0.f};
          s = MFMA16(kf0, qf[fq][0], s);
          s = MFMA16(kf1, qf[fq][1], s);
          i32x4 m4 = *(const i32x4*)(mb + (size_t)qrow * LSEQ + k0 + fn * 16 + lg * 4);
          den[fq] += (m4[0] != 0) ? EXP2F(s[0]) : 0.f;
          den[fq] += (m4[1] != 0) ? EXP2F(s[1]) : 0.f;
          den[fq] += (m4[2] != 0) ? EXP2F(s[2]) : 0.f;
          den[fq] += (m4[3] != 0) ? EXP2F(s[3]) : 0.f;
        }
      }
    }
  }
  float inv[2];
#pragma unroll
  for (int fq = 0; fq < 2; fq++) {
    den[fq] += __shfl_xor(den[fq], 16);
    den[fq] += __shfl_xor(den[fq], 32);
    inv[fq] = 1.0f / den[fq];
  }

  // ---------------- sweep 2: Ps build + PV + 512B coalesced attn store ----------
  f32x4 oacc[2][4];
#pragma unroll
  for (int fq = 0; fq < 2; fq++)
#pragma unroll
    for (int fd = 0; fd < 4; fd++) oacc[fq][fd] = (f32x4){0.f, 0.f, 0.f, 0.f};

#pragma unroll
  for (int j = 0; j < 4; j++) ka[j] = *(const short8*)(Kst + j * 8);

  const unsigned short* Vbase = Vh + (size_t)l15 * LSEQ + lg * 8;

  for (int kt = 0; kt < NT; ++kt) {
    const int k0 = kt * 128;
    __syncthreads();
#pragma unroll
    for (int j = 0; j < 4; j++)
      *(short8*)&Ks[sr * 64 + (((((tid & 1) * 64) + j * 16) ^ swz_w) >> 1)] = ka[j];
    __syncthreads();
    if (kt + 1 < NT) {
#pragma unroll
      for (int j = 0; j < 4; j++)
        ka[j] = *(const short8*)(Kst + (size_t)(kt + 1) * 128 * DMOD + j * 8);
    }
    short8 vf[4][4];
#pragma unroll
    for (int fd = 0; fd < 4; fd++)
#pragma unroll
      for (int ks = 0; ks < 4; ks++)
        vf[fd][ks] = *(const short8*)(Vbase + (size_t)(fd * 16) * LSEQ + k0 + ks * 32);

    const bool fast = frow[kt] != 0;
    if (fast) {
#pragma unroll
      for (int fn = 0; fn < 8; fn++) {
        const int krow = fn * 16 + l15;
        const int rb = krow * 64, rx = (krow & 7) << 4;
        short8 kf0 = *(const short8*)&Ks[rb + (((lg * 16) ^ rx) >> 1)];
        short8 kf1 = *(const short8*)&Ks[rb + (((64 + lg * 16) ^ rx) >> 1)];
#pragma unroll
        for (int fq = 0; fq < 2; fq++) {
          f32x4 s = (f32x4){0.f, 0.f, 0.f, 0.f};
          s = MFMA16(kf0, qf[fq][0], s);
          s = MFMA16(kf1, qf[fq][1], s);
          f32x4 a;
          a[0] = EXP2F(s[0]) * inv[fq];
          a[1] = EXP2F(s[1]) * inv[fq];
          a[2] = EXP2F(s[2]) * inv[fq];
          a[3] = EXP2F(s[3]) * inv[fq];
          union { u16x4 pk; unsigned u[2]; } P;
          P.u[0] = cvt_pk_bf16(a[0], a[1]);
          P.u[1] = cvt_pk_bf16(a[2], a[3]);
          *(u16x4*)&Ps[wid][fq * 16 + l15][fn * 16 + lg * 4] = P.pk;
        }
      }
    } else {
#pragma unroll
      for (int fn = 0; fn < 8; fn++) {
        const int krow = fn * 16 + l15;
        const int rb = krow * 64, rx = (krow & 7) << 4;
        short8 kf0 = *(const short8*)&Ks[rb + (((lg * 16) ^ rx) >> 1)];
        short8 kf1 = *(const short8*)&Ks[rb + (((64 + lg * 16) ^ rx) >> 1)];
#pragma unroll
        for (int fq = 0; fq < 2; fq++) {
          const int qrow = wq0 + fq * 16 + l15;
          f32x4 s = (f32x4){0.f, 0.f, 0.f, 0.f};
          s = MFMA16(kf0, qf[fq][0], s);
          s = MFMA16(kf1, qf[fq][1], s);
          i32x4 m4 = *(const i32x4*)(mb + (size_t)qrow * LSEQ + k0 + fn * 16 + lg * 4);
          f32x4 a;
          a[0] = (m4[0] != 0) ? EXP2F(s[0]) * inv[fq] : 0.f;
          a[1] = (m4[1] != 0) ? EXP2F(s[1]) * inv[fq] : 0.f;
          a[2] = (m4[2] != 0) ? EXP2F(s[2]) * inv[fq] : 0.f;
          a[3] = (m4[3] != 0) ? EXP2F(s[3]) * inv[fq] : 0.f;
          union { u16x4 pk; unsigned u[2]; } P;
          P.u[0] = cvt_pk_bf16(a[0], a[1]);
          P.u[1] = cvt_pk_bf16(a[2], a[3]);
          *(u16x4*)&Ps[wid][fq * 16 + l15][fn * 16 + lg * 4] = P.pk;
        }
      }
    }
    // PV: A = Ps rows (wave-private), B = V^T rows (registers); full 128-k
    short8 pa2[2][4];
#pragma unroll
    for (int fq = 0; fq < 2; fq++)
#pragma unroll
      for (int ks = 0; ks < 4; ks++)
        pa2[fq][ks] = *(const short8*)&Ps[wid][fq * 16 + l15][ks * 32 + lg * 8];
#pragma unroll
    for (int fd = 0; fd < 4; fd++)
#pragma unroll
      for (int fq = 0; fq < 2; fq++)
#pragma unroll
        for (int ks = 0; ks < 4; ks++)
          oacc[fq][fd] = MFMA16(pa2[fq][ks], vf[fd][ks], oacc[fq][fd]);

    // coalesced attn store: per instruction, 2 full rows x 512B contiguous
    {
      float* abase = ah + (size_t)wq0 * LSEQ + k0;
      const int rsel = lane >> 5, csel = (lane & 31) * 4;
#pragma unroll
      for (int i = 0; i < 16; i++) {
        const int qoff = i * 2 + rsel;
        unsigned long long d = *(const unsigned long long*)&Ps[wid][qoff][csel];
        unsigned d0 = (unsigned)d, d1 = (unsigned)(d >> 32);
        union { unsigned u; float f; } t0, t1, t2, t3;
        t0.u = d0 << 16;
        t1.u = d0 & 0xffff0000u;
        t2.u = d1 << 16;
        t3.u = d1 & 0xffff0000u;
        f32x4 a = (f32x4){t0.f, t1.f, t2.f, t3.f};
        __builtin_nontemporal_store(a, (f32x4*)(abase + (size_t)qoff * LSEQ + csel));
      }
    }
  }

  // ---------------- ctx store (no k-split reduction needed) ----------------
  unsigned short* ch = ctx + (size_t)b * LSEQ * DMOD + h * HDSZ;
#pragma unroll
  for (int fq = 0; fq < 2; fq++)
#pragma unroll
    for (int fd = 0; fd < 4; fd++) {
      u16x4 pk = pack4_pk(oacc[fq][fd][0], oacc[fq][fd][1], oacc[fq][fd][2],
                          oacc[fq][fd][3]);
#pragma unroll
      for (int r = 0; r < 4; r++) {
        const int qr = wq0 + fq * 16 + lg * 4 + r;
        ch[(size_t)qr * DMOD + fd * 16 + l15] = pk[r];
      }
    }
}

// ---------------- launcher ----------------
extern "C" void kernel_launch(void* const* d_in, const int* in_sizes, int n_in,
                              void* d_out, int out_size, void* d_ws, size_t ws_size,
                              hipStream_t stream) {
  const float* q = (const float*)d_in[0];
  const float* k = (const float*)d_in[1];
  const float* v = (const float*)d_in[2];
  const int* mask = (const int*)d_in[3];
  const float* Wq = (const float*)d_in[4];
  const float* bq = (const float*)d_in[5];
  const float* Wk = (const float*)d_in[6];
  const float* bk = (const float*)d_in[7];
  const float* Wv = (const float*)d_in[8];
  const float* bv = (const float*)d_in[9];
  const float* Wo = (const float*)d_in[10];
  const float* bo = (const float*)d_in[11];

  float* out = (float*)d_out;
  float* attn = out + (size_t)BSZ * LSEQ * DMOD;

  const size_t NQKV = (size_t)BSZ * LSEQ * DMOD;

  int* flags = (int*)out;  // 512 ints; overwritten by final out-proj

  unsigned short* Qp = (unsigned short*)d_ws;
  unsigned short* Kp = Qp + NQKV;
  unsigned short* Vt = Kp + NQKV;  // (B, D, L)
  unsigned short* ctx = Vt + NQKV;

  // QKV projections (z=0..2) + fused mask-check (z=3, overlaps GEMM).
  // Q scale = 0.125 * log2(e) (exp2-folded softmax).
  gemm_bt<1, 0><<<dim3(32, 8, 4), 256, 0, stream>>>(
      q, k, v, Wq, Wk, Wv, bq, bk, bv, (void*)Qp, (void*)Kp, (void*)Vt,
      0.18033688011112042f, 1.0f, 1.0f, /*vtz=*/2, BSZ * LSEQ, DMOD, DMOD, mask, flags);

  attn_kernel<<<dim3(LSEQ / 128, BSZ * NH), 256, 0, stream>>>(Qp, Kp, Vt, mask, flags,
                                                              attn, ctx);

  gemm_bt<0, 1><<<dim3(32, 8, 1), 256, 0, stream>>>(
      ctx, ctx, ctx, Wo, Wo, Wo, bo, bo, bo, (void*)out, (void*)out, (void*)out,
      1.0f, 1.0f, 1.0f, /*vtz=*/-1, BSZ * LSEQ, DMOD, DMOD, nullptr, nullptr);
}